// Round 4
// baseline (549.709 us; speedup 1.0000x reference)
//
#include <hip/hip_runtime.h>
#include <hip/hip_bf16.h>

// Problem constants (CrossNetMixFuxiCTR): B=16384, D=2048, L=3, E=8, R=64
#define BDIM 16384
#define DDIM 2048
#define LNUM 3
#define ENUM 8
#define NP 24            // L*E (l,e) pairs

// GEMM tile
#define BM 256           // rows per block (4 waves x 64 rows)
#define BK 64            // f16 k-elements per iter (4 k16-windows)
#define NKIT (DDIM / BK) // 32 k-iterations

typedef _Float16 f16x8 __attribute__((ext_vector_type(8)));
typedef _Float16 f16x4 __attribute__((ext_vector_type(4)));
typedef float f32x16 __attribute__((ext_vector_type(16)));

// Fragment-major layout (both X0f and Whf): data grouped in 1024-B blocks.
// Block (g32, kw) holds rows g32*32..+31, k = kw*16..+15. Within the block,
// lane L's 16-B chunk (8 f16) is at offset L*16, where L = khalf*32 + row,
// khalf = (k>>3)&1, row = m&31. This makes the mfma_32x32x16 A/B operand
// read = 64 consecutive 16-B chunks (coalesced global dwordx4 per lane, or
// conflict-free contiguous ds_read_b128 from LDS).

// ------- convert U,V -> Whf f16 fragment-major: [p][gn(4)][kw(128)][64 chunks] -------
__global__ void cvt_w_kernel(const float* __restrict__ U, const float* __restrict__ V,
                             _Float16* __restrict__ Whf) {
    int idx = blockIdx.x * 256 + threadIdx.x;    // one 16-B chunk (8 k) of one row
    int f8     = idx & 255;                      // k-chunk within row (k = f8*8)
    int row128 = (idx >> 8) & 127;               // 0..63 U, 64..127 V
    int p      = idx >> 15;
    const float* src = (row128 < 64)
        ? (U + ((size_t)(p * 64 + row128) * DDIM + f8 * 8))
        : (V + ((size_t)(p * 64 + (row128 - 64)) * DDIM + f8 * 8));
    float4 a = ((const float4*)src)[0];
    float4 b = ((const float4*)src)[1];
    f16x8 h = { (_Float16)a.x, (_Float16)a.y, (_Float16)a.z, (_Float16)a.w,
                (_Float16)b.x, (_Float16)b.y, (_Float16)b.z, (_Float16)b.w };
    int gn = row128 >> 5, col = row128 & 31;
    int kw = f8 >> 1, khalf = f8 & 1;
    size_t C = ((size_t)((p * 4 + gn) * 128 + kw)) * 64 + khalf * 32 + col;
    ((f16x8*)Whf)[C] = h;
}

// ---- fused: gate logits G[j][b] = X0[b].Wg[j] (fp32) + X0 -> X0f (f16 fragment-major) ----
// 32 rows/block (512 blocks = 2/CU). Thread: 1 row (rq=tid>>3), 1/8 of k (q=tid&7).
// Wg staged in LDS (24 KB); acc[24] regs -> no spill.
__global__ __launch_bounds__(256, 2) void gate_kernel(
    const float* __restrict__ X0, const float* __restrict__ Wg,
    float* __restrict__ G, _Float16* __restrict__ X0f) {
    __shared__ float Wgs[NP * 256];   // 24 KB
    const int tid = (int)threadIdx.x;
    const int rq  = tid >> 3;          // 0..31 row within block
    const int q   = tid & 7;           // k-slice
    const int r0  = blockIdx.x * 32 + rq;
    const int g32 = blockIdx.x;        // 32-row group index

    float acc[NP];
#pragma unroll
    for (int j = 0; j < NP; ++j) acc[j] = 0.f;

    const float4* xp = (const float4*)(X0 + (size_t)r0 * DDIM);

    for (int k0 = 0; k0 < DDIM; k0 += 256) {
        __syncthreads();
#pragma unroll
        for (int t = tid; t < NP * 64; t += 256)
            ((float4*)Wgs)[t] =
                ((const float4*)Wg)[(size_t)(t >> 6) * (DDIM / 4) + (k0 >> 2) + (t & 63)];
        __syncthreads();
#pragma unroll 2
        for (int i = 0; i < 4; ++i) {
            int f8 = i * 8 + q;                   // 8-f16 chunk within 256-k window
            int gcf4 = (k0 >> 2) + f8 * 2;        // float4 column
            float4 xa = xp[gcf4];
            float4 xb = xp[gcf4 + 1];
            f16x8 h = { (_Float16)xa.x, (_Float16)xa.y, (_Float16)xa.z, (_Float16)xa.w,
                        (_Float16)xb.x, (_Float16)xb.y, (_Float16)xb.z, (_Float16)xb.w };
            int kw = (k0 >> 4) + (f8 >> 1);
            int khalf = f8 & 1;
            ((f16x8*)X0f)[((size_t)(g32 * 128 + kw)) * 64 + khalf * 32 + rq] = h;
#pragma unroll
            for (int j = 0; j < NP; ++j) {
                float4 wa = ((const float4*)(Wgs + j * 256))[f8 * 2];
                float4 wb = ((const float4*)(Wgs + j * 256))[f8 * 2 + 1];
                acc[j] += xa.x * wa.x + xa.y * wa.y + xa.z * wa.z + xa.w * wa.w
                        + xb.x * wb.x + xb.y * wb.y + xb.z * wb.z + xb.w * wb.w;
            }
        }
    }
#pragma unroll
    for (int j = 0; j < NP; ++j) {
        float v = acc[j];
        v += __shfl_xor(v, 1);
        v += __shfl_xor(v, 2);
        v += __shfl_xor(v, 4);
        if (q == 0) G[(size_t)j * BDIM + r0] = v;
    }
}

// ---------------- MFMA GEMM (32x32x16) + in-wave bilinear reduction ----------------
// Block: 256 thr (4 waves), tile 256 rows x 128 cols (one p: cols 0-63 PU, 64-127 PV).
// A fragments load DIRECTLY global->VGPR from fragment-major X0f (coalesced 1024-B
// wave reads, LLC-resident) — A never touches LDS. B staged via global_load_lds into
// double-buffered fragment-major LDS (32 KB), read as contiguous conflict-free b128.
// One barrier per BK=64 k-iter; staged B + prefetched A get the whole MFMA phase to land.
__global__ __launch_bounds__(256, 2) void gemm_t_kernel(
    const _Float16* __restrict__ X0f,  // fragment-major A
    const _Float16* __restrict__ Whf,  // fragment-major B
    float* __restrict__ T)             // [NP][BDIM]
{
    const int p    = blockIdx.y;
    const int m0   = blockIdx.x * BM;
    const int tid  = (int)threadIdx.x;
    const int wave = tid >> 6;
    const int lane = tid & 63;

    __shared__ _Float16 Bs[2 * 16 * 512];   // 2 bufs x (4 gn x 4 kw) x 1024 B = 32 KB

    const int g32b = (m0 >> 5) + wave * 2;  // this wave's first 32-row group

    f32x16 acc[2][4];                       // [mt][gn]
#pragma unroll
    for (int i = 0; i < 2; ++i)
#pragma unroll
        for (int j = 0; j < 4; ++j) acc[i][j] = (f32x16)(0.f);

    f16x8 aF[2][8];                         // [pingpong][mt*4+kw]

    // prologue: stage B buf0 + load A frags for it=0
#pragma unroll
    for (int kw = 0; kw < 4; ++kw) {
        const _Float16* gb = Whf + (((size_t)((p * 4 + wave) * 128 + kw)) * 64 + lane) * 8;
        __builtin_amdgcn_global_load_lds(
            (const __attribute__((address_space(1))) void*)gb,
            (__attribute__((address_space(3))) void*)&Bs[(wave * 4 + kw) * 512], 16, 0, 0);
    }
#pragma unroll
    for (int mt = 0; mt < 2; ++mt)
#pragma unroll
        for (int kw = 0; kw < 4; ++kw)
            aF[0][mt * 4 + kw] = *(const f16x8*)(
                X0f + (((size_t)((g32b + mt) * 128 + kw)) * 64 + lane) * 8);
    __syncthreads();

#pragma unroll 2
    for (int it = 0; it < NKIT; ++it) {
        const int cur = it & 1, nxt = cur ^ 1;
        if (it != NKIT - 1) {
            const int kwn = (it + 1) * 4;   // next iter's first k16-window
#pragma unroll
            for (int kw = 0; kw < 4; ++kw) {
                const _Float16* gb =
                    Whf + (((size_t)((p * 4 + wave) * 128 + kwn + kw)) * 64 + lane) * 8;
                __builtin_amdgcn_global_load_lds(
                    (const __attribute__((address_space(1))) void*)gb,
                    (__attribute__((address_space(3))) void*)&Bs[(nxt * 16 + wave * 4 + kw) * 512],
                    16, 0, 0);
            }
#pragma unroll
            for (int mt = 0; mt < 2; ++mt)
#pragma unroll
                for (int kw = 0; kw < 4; ++kw)
                    aF[nxt][mt * 4 + kw] = *(const f16x8*)(
                        X0f + (((size_t)((g32b + mt) * 128 + kwn + kw)) * 64 + lane) * 8);
        }
#pragma unroll
        for (int kw = 0; kw < 4; ++kw) {
            f16x8 bF[4];
#pragma unroll
            for (int gn = 0; gn < 4; ++gn)
                bF[gn] = *(const f16x8*)&Bs[((cur * 16 + gn * 4 + kw) * 64 + lane) * 8];
#pragma unroll
            for (int mt = 0; mt < 2; ++mt)
#pragma unroll
                for (int gn = 0; gn < 4; ++gn)
                    acc[mt][gn] = __builtin_amdgcn_mfma_f32_32x32x16_f16(
                        aF[cur][mt * 4 + kw], bF[gn], acc[mt][gn], 0, 0, 0);
        }
        __syncthreads();   // all waves done reading Bs[cur]; drains next-iter staging
    }

    // C/D layout (32x32x16, verified): col = lane&31, row = (reg&3) + 8*(reg>>2) + 4*(lane>>5).
    // PU col c at gn=c>>5 (0,1); PV col c at gn=2+(c>>5) — same lane, same reg.
#pragma unroll
    for (int mt = 0; mt < 2; ++mt) {
#pragma unroll
        for (int reg = 0; reg < 16; ++reg) {
            float tp = acc[mt][0][reg] * acc[mt][2][reg]
                     + acc[mt][1][reg] * acc[mt][3][reg];
            tp += __shfl_xor(tp, 1);
            tp += __shfl_xor(tp, 2);
            tp += __shfl_xor(tp, 4);
            tp += __shfl_xor(tp, 8);
            tp += __shfl_xor(tp, 16);
            if ((lane & 31) == 0) {
                int row = (reg & 3) + 8 * (reg >> 2) + 4 * (lane >> 5);
                T[(size_t)p * BDIM + m0 + wave * 64 + mt * 32 + row] = tp;
            }
        }
    }
}

// ---------------- per-row scalar recurrence + scaled write-out (reads X0f) ----------------
__global__ void epilogue_kernel(const _Float16* __restrict__ X0f,
                                const float* __restrict__ T,
                                const float* __restrict__ G,
                                const float* __restrict__ bg,
                                float* __restrict__ out) {
    __shared__ float s_sh[16];
    const int b0 = blockIdx.x * 16;
    const int tid = (int)threadIdx.x;
    if (tid < 16) {
        int b = b0 + tid;
        float s = 1.f;
#pragma unroll
        for (int l = 0; l < LNUM; ++l) {
            float logit[ENUM];
            float mx = -1e30f;
#pragma unroll
            for (int e = 0; e < ENUM; ++e) {
                int j = l * ENUM + e;
                float g = s * G[(size_t)j * BDIM + b] + bg[j];
                logit[e] = g;
                mx = fmaxf(mx, g);
            }
            float den = 0.f, num = 0.f;
            float s2 = s * s;
#pragma unroll
            for (int e = 0; e < ENUM; ++e) {
                int j = l * ENUM + e;
                float w = __expf(logit[e] - mx);
                den += w;
                num += w * (s2 * T[(size_t)j * BDIM + b]);
            }
            s += num / den;
        }
        s_sh[tid] = s;
    }
    __syncthreads();
    // 16 rows x 256 chunks (8 f16 each); one row per pass -> coalesced 4-KB row writes
    for (int idx = tid; idx < 16 * 256; idx += 256) {
        int r = idx >> 8;
        int c = idx & 255;
        int rg = b0 + r;
        float s = s_sh[r];
        f16x8 h = ((const f16x8*)X0f)[((size_t)((rg >> 5) * 128 + (c >> 1))) * 64
                                      + (c & 1) * 32 + (rg & 31)];
        float4 o0 = { s * (float)h[0], s * (float)h[1], s * (float)h[2], s * (float)h[3] };
        float4 o1 = { s * (float)h[4], s * (float)h[5], s * (float)h[6], s * (float)h[7] };
        float4* op = (float4*)(out + (size_t)rg * DDIM + c * 8);
        op[0] = o0;
        op[1] = o1;
    }
}

extern "C" void kernel_launch(void* const* d_in, const int* in_sizes, int n_in,
                              void* d_out, int out_size, void* d_ws, size_t ws_size,
                              hipStream_t stream) {
    const float* X0 = (const float*)d_in[0];
    const float* U  = (const float*)d_in[1];
    const float* V  = (const float*)d_in[2];
    const float* Wg = (const float*)d_in[3];
    const float* bg = (const float*)d_in[4];
    float* out = (float*)d_out;

    // workspace layout (~83 MB)
    char* ws = (char*)d_ws;
    _Float16* X0f = (_Float16*)ws;                                   // 67108864 B
    _Float16* Whf = (_Float16*)(ws + 67108864ull);                   // 12582912 B
    float* T      = (float*)(ws + 67108864ull + 12582912ull);        // 1572864 B
    float* G      = (float*)(ws + 67108864ull + 12582912ull + 1572864ull);

    cvt_w_kernel<<<dim3(NP * 128 * 256 / 256), dim3(256), 0, stream>>>(U, V, Whf);
    gate_kernel<<<dim3(BDIM / 32), dim3(256), 0, stream>>>(X0, Wg, G, X0f);
    gemm_t_kernel<<<dim3(BDIM / BM, NP), dim3(256), 0, stream>>>(X0f, Whf, T);
    epilogue_kernel<<<dim3(BDIM / 16), dim3(256), 0, stream>>>(X0f, T, G, bg, out);
}